// Round 11
// baseline (118.182 us; speedup 1.0000x reference)
//
#include <hip/hip_runtime.h>
#include <hip/hip_bf16.h>
#include <math.h>

#define S_LEN 1024
#define DM    256
#define DU    32
#define TEMPF 5.0f

typedef float    f32x4  __attribute__((ext_vector_type(4)));
typedef short    bf16x8 __attribute__((ext_vector_type(8)));   // 8 bf16 (4 VGPRs)
typedef _Float16 f16x2  __attribute__((ext_vector_type(2)));
typedef _Float16 f16x8  __attribute__((ext_vector_type(8)));

// task table: it4<8 -> NS=4, it4>=8 -> NS=8; 96 tasks per head
__device__ __host__ inline int task_cnt(int it4)  { return it4 < 8 ? 4 : 8; }
__device__ __host__ inline int task_base(int it4) { return it4 < 8 ? it4 * 4 : 32 + (it4 - 8) * 8; }

__device__ __forceinline__ unsigned short f32_to_bf16_rne(float x) {
    unsigned int b = __float_as_uint(x);
    b += 0x7FFFu + ((b >> 16) & 1u);
    return (unsigned short)(b >> 16);
}

// split f into bf16 hi + bf16 lo (hi+lo ~= f to ~2^-17 rel)
__device__ __forceinline__ void split_bf16(float f, unsigned short& h, unsigned short& l) {
    h = f32_to_bf16_rne(f);
    float hf = __uint_as_float((unsigned int)h << 16);
    l = f32_to_bf16_rne(f - hf);
}

// ---------------------------------------------------------------------------
// Kernel A: fused QKV projection via split-bf16 MFMA.
// 32x64 tiles -> 384 blocks (1.5/CU) for 2-wave/SIMD latency hiding.
// Wave w: m-half = w&1 (16 rows), n-tiles {2*(w>>1), 2*(w>>1)+1}.
// ---------------------------------------------------------------------------
__global__ __launch_bounds__(256, 2) void qkv_proj_kernel(
    const float* __restrict__ x,
    const float* __restrict__ Wq, const float* __restrict__ bq,
    const float* __restrict__ Wk, const float* __restrict__ bk,
    const float* __restrict__ Wv, const float* __restrict__ bv,
    float* __restrict__ qo, float* __restrict__ ko, float* __restrict__ vo)
{
    const int n0g = blockIdx.x * 64;       // 0..704 over [Wq|Wk|Wv] cols
    const int mat = n0g >> 8;
    const int n0  = n0g & 255;
    const float* __restrict__ W    = (mat == 0) ? Wq : ((mat == 1) ? Wk : Wv);
    const float* __restrict__ bias = (mat == 0) ? bq : ((mat == 1) ? bk : bv);
    float* __restrict__ dst        = (mat == 0) ? qo : ((mat == 1) ? ko : vo);

    const int m0   = blockIdx.y * 32;
    const int t    = threadIdx.x;
    const int w    = t >> 6;
    const int lane = t & 63;
    const int fm   = lane & 15;
    const int quad = lane >> 4;
    const int q8   = quad * 8;
    const int mh   = w & 1;            // m-half (16 rows)
    const int nb2  = (w >> 1) * 2;     // first of 2 n-tiles

    __shared__ __align__(16) unsigned short Ah[2][32][40], Al[2][32][40];
    __shared__ __align__(16) unsigned short Bh[2][64][40], Bl[2][64][40];

    const int xr  = t >> 3;          // A row 0..31
    const int xf  = (t & 7) * 4;     // A k-offset 0..28
    const int wn  = t & 63;          // B col 0..63
    const int wkc = (t >> 6) * 8;    // B k-chunk 0,8,16,24

    f32x4 acc[2];
    #pragma unroll
    for (int nt = 0; nt < 2; nt++)
        #pragma unroll
        for (int i = 0; i < 4; i++) acc[nt][i] = 0.0f;

    const float* xbase = x + (m0 + xr) * DM + xf;
    float xa[4], wv[8];

    auto loadX = [&](int k0) {
        float4 a0 = *(const float4*)(xbase + k0);
        xa[0]=a0.x; xa[1]=a0.y; xa[2]=a0.z; xa[3]=a0.w;
    };
    auto loadW = [&](int k0) {
        #pragma unroll
        for (int i = 0; i < 8; i++) wv[i] = W[(k0 + wkc + i) * DM + n0 + wn];
    };
    auto storeT = [&](int b) {
        ushort4 ah4, al4;
        unsigned short hh, ll;
        split_bf16(xa[0], hh, ll); ah4.x = hh; al4.x = ll;
        split_bf16(xa[1], hh, ll); ah4.y = hh; al4.y = ll;
        split_bf16(xa[2], hh, ll); ah4.z = hh; al4.z = ll;
        split_bf16(xa[3], hh, ll); ah4.w = hh; al4.w = ll;
        *(ushort4*)&Ah[b][xr][xf] = ah4;
        *(ushort4*)&Al[b][xr][xf] = al4;
        bf16x8 vh, vl;
        #pragma unroll
        for (int i = 0; i < 8; i++) { unsigned short h2,l2; split_bf16(wv[i],h2,l2); vh[i]=(short)h2; vl[i]=(short)l2; }
        *(bf16x8*)&Bh[b][wn][wkc] = vh; *(bf16x8*)&Bl[b][wn][wkc] = vl;
    };

    loadX(0); loadW(0);
    storeT(0);
    __syncthreads();

    int buf = 0;
    for (int step = 0; step < 8; step++) {
        if (step < 7) { loadX((step + 1) * 32); loadW((step + 1) * 32); }
        {
            bf16x8 ah = *(const bf16x8*)&Ah[buf][16 * mh + fm][q8];
            bf16x8 al = *(const bf16x8*)&Al[buf][16 * mh + fm][q8];
            #pragma unroll
            for (int nt = 0; nt < 2; nt++) {
                bf16x8 bh = *(const bf16x8*)&Bh[buf][(nb2 + nt) * 16 + fm][q8];
                bf16x8 bl = *(const bf16x8*)&Bl[buf][(nb2 + nt) * 16 + fm][q8];
                acc[nt] = __builtin_amdgcn_mfma_f32_16x16x32_bf16(ah, bh, acc[nt], 0, 0, 0);
                acc[nt] = __builtin_amdgcn_mfma_f32_16x16x32_bf16(al, bh, acc[nt], 0, 0, 0);
                acc[nt] = __builtin_amdgcn_mfma_f32_16x16x32_bf16(ah, bl, acc[nt], 0, 0, 0);
            }
        }
        if (step < 7) {
            const int nb = buf ^ 1;
            storeT(nb);
            __syncthreads();
            buf = nb;
        }
    }

    #pragma unroll
    for (int nt = 0; nt < 2; nt++) {
        const int col = n0 + (nb2 + nt) * 16 + fm;
        const float bb = bias[col];
        const int hh = col >> 5;
        const int dd = col & 31;
        float* dp = dst + hh * (S_LEN * DU) + dd;
        #pragma unroll
        for (int reg = 0; reg < 4; reg++) {
            const int row = m0 + 16 * mh + quad * 4 + reg;
            float val = acc[nt][reg] + bb;
            if (mat < 2) val = 1.0f / (1.0f + __expf(-val));
            dp[row * DU] = val;
        }
    }
}

// ---------------------------------------------------------------------------
// Kernel B: fuzzy-implication attention.  Variable j-split: NS=4 (it4<8),
// NS=8 (it4>=8) -> 768 blocks (3/CU); every task with it4>=4 runs exactly
// 2 j-tiles -> critical path halved.  f16 score + bf16 MFMA PV (proven).
// ---------------------------------------------------------------------------
__global__ __launch_bounds__(256, 3) void attn_kernel(
    const float* __restrict__ q, const float* __restrict__ k,
    const float* __restrict__ v,
    float* __restrict__ part_o, float* __restrict__ part_l)
{
    const int bid = blockIdx.x;
    const int h   = bid / 96;
    const int rm  = bid - h * 96;
    int it4, s, NSi;
    if (rm < 32) { it4 = rm >> 2;        s = rm & 3;         NSi = 4; }
    else         { it4 = 8 + ((rm - 32) >> 3); s = (rm - 32) & 7; NSi = 8; }
    const int t   = threadIdx.x;
    const int r   = t >> 4;               // 0..15
    const int c   = t & 15;               // 0..15
    const int w   = t >> 6;               // wave 0..3
    const int i0  = it4 * 64;

    __shared__ __align__(16) _Float16       Kh[64][40];   // [j][d] f16 (score)
    __shared__ __align__(16) unsigned short Vt[32][88];   // [d][j] bf16 (B-op)
    __shared__ __align__(16) unsigned short Ps[64][88];   // [row][j] bf16 (A-op)

    // Q rows as f16x2 pairs
    f16x2 qh[4][16];
    #pragma unroll
    for (int kq = 0; kq < 4; kq++) {
        const float* qrow = q + h * (S_LEN * DU) + (i0 + r + 16 * kq) * DU;
        #pragma unroll
        for (int d4 = 0; d4 < 8; d4++) {
            float4 qv = *(const float4*)&qrow[d4 * 4];
            qh[kq][d4*2+0] = (f16x2){(_Float16)qv.x, (_Float16)qv.y};
            qh[kq][d4*2+1] = (f16x2){(_Float16)qv.z, (_Float16)qv.w};
        }
    }
    const f16x2 one2  = {(_Float16)1.0f, (_Float16)1.0f};
    const f16x2 zero2 = {(_Float16)0.0f, (_Float16)0.0f};

    float lpart[4] = {0.0f, 0.0f, 0.0f, 0.0f};
    f32x4 acc0 = {0.0f, 0.0f, 0.0f, 0.0f};
    f32x4 acc1 = {0.0f, 0.0f, 0.0f, 0.0f};

    const int jr = t >> 2;
    const int d0 = (t & 3) * 8;
    const float* kbase = k + h * (S_LEN * DU);
    const float* vbase = v + h * (S_LEN * DU);

    const int lane = t & 63;
    const int m    = lane & 15;
    const int quad = lane >> 4;

    const int njt = it4 + 1;
    float4 ka, kb, va, vb;
    if (s < njt) {
        const float* kp = kbase + (s * 64 + jr) * DU + d0;
        const float* vp = vbase + (s * 64 + jr) * DU + d0;
        ka = *(const float4*)kp; kb = *(const float4*)(kp + 4);
        va = *(const float4*)vp; vb = *(const float4*)(vp + 4);
    }

    for (int jt = s; jt < njt; jt += NSi) {
        __syncthreads();
        {
            float kv[8] = {ka.x, ka.y, ka.z, ka.w, kb.x, kb.y, kb.z, kb.w};
            f16x8 kh8;
            #pragma unroll
            for (int i = 0; i < 8; i++) kh8[i] = (_Float16)kv[i];
            *(f16x8*)&Kh[jr][d0] = kh8;
            float vv[8] = {va.x, va.y, va.z, va.w, vb.x, vb.y, vb.z, vb.w};
            #pragma unroll
            for (int i = 0; i < 8; i++)
                Vt[d0 + i][jr] = f32_to_bf16_rne(vv[i]);
        }
        __syncthreads();
        if (jt + NSi < njt) {
            const float* kp = kbase + ((jt + NSi) * 64 + jr) * DU + d0;
            const float* vp = vbase + ((jt + NSi) * 64 + jr) * DU + d0;
            ka = *(const float4*)kp; kb = *(const float4*)(kp + 4);
            va = *(const float4*)vp; vb = *(const float4*)(vp + 4);
        }

        // ---- phase 1: f16-packed scores -> p -> Ps bf16 + l partials ----
        #pragma unroll
        for (int q4 = 0; q4 < 4; q4++) {
            const int jj  = c + q4 * 16;
            const int jgl = jt * 64 + jj;
            float sacc[4] = {0.0f, 0.0f, 0.0f, 0.0f};
            #pragma unroll
            for (int d8 = 0; d8 < 4; d8++) {
                f16x8 k8 = *(const f16x8*)&Kh[jj][d8 * 8];
                #pragma unroll
                for (int p2 = 0; p2 < 4; p2++) {
                    f16x2 kk = {k8[2*p2], k8[2*p2+1]};
                    #pragma unroll
                    for (int kq = 0; kq < 4; kq++) {
                        f16x2 diff = qh[kq][d8*4+p2] - kk;
                        f16x2 mx = __builtin_elementwise_max(diff, zero2);
#if defined(__has_builtin) && __has_builtin(__builtin_amdgcn_fdot2)
                        sacc[kq] = __builtin_amdgcn_fdot2(mx, one2, sacc[kq], false);
#else
                        sacc[kq] += (float)mx[0] + (float)mx[1];
#endif
                    }
                }
            }
            #pragma unroll
            for (int kq = 0; kq < 4; kq++) {
                const int ig = i0 + r + 16 * kq;
                const float p = (jgl <= ig)
                    ? __expf(TEMPF - (TEMPF / 32.0f) * sacc[kq]) : 0.0f;
                lpart[kq] += p;
                Ps[r + 16 * kq][jj] = f32_to_bf16_rne(p);
            }
        }
        __syncthreads();

        // ---- phase 2: PV via MFMA ----
        #pragma unroll
        for (int kc = 0; kc < 2; kc++) {
            bf16x8 a  = *(const bf16x8*)&Ps[16 * w + m][kc * 32 + quad * 8];
            bf16x8 b0 = *(const bf16x8*)&Vt[m]     [kc * 32 + quad * 8];
            bf16x8 b1 = *(const bf16x8*)&Vt[m + 16][kc * 32 + quad * 8];
            acc0 = __builtin_amdgcn_mfma_f32_16x16x32_bf16(a, b0, acc0, 0, 0, 0);
            acc1 = __builtin_amdgcn_mfma_f32_16x16x32_bf16(a, b1, acc1, 0, 0, 0);
        }
    }

    #pragma unroll
    for (int off = 8; off; off >>= 1)
        #pragma unroll
        for (int kq = 0; kq < 4; kq++)
            lpart[kq] += __shfl_xor(lpart[kq], off, 16);

    const int pbase = h * 96 + task_base(it4) + s;
    float* po = part_o + (size_t)pbase * 2048;
    #pragma unroll
    for (int reg = 0; reg < 4; reg++) {
        const int row = 16 * w + quad * 4 + reg;
        po[row * 32 + m]      = acc0[reg];
        po[row * 32 + m + 16] = acc1[reg];
    }
    if (c == 0) {
        #pragma unroll
        for (int kq = 0; kq < 4; kq++)
            part_l[pbase * 64 + r + 16 * kq] = lpart[kq];
    }
}

// ---------------------------------------------------------------------------
// Kernel C: output projection + fused combine.  32x32 tiles -> 256 blocks
// (full-chip coverage).  Wave w: m-half = w&1, n-half = w>>1.
// ---------------------------------------------------------------------------
__global__ __launch_bounds__(256, 2) void out_proj_kernel(
    const float* __restrict__ part_o, const float* __restrict__ part_l,
    const float* __restrict__ W, const float* __restrict__ bias,
    float* __restrict__ dst)
{
    const int n0   = blockIdx.x * 32;
    const int m0   = blockIdx.y * 32;
    const int it4  = m0 >> 6;
    const int half = m0 & 32;          // row offset within the it4 tile
    const int t    = threadIdx.x;
    const int w    = t >> 6;
    const int lane = t & 63;
    const int fm   = lane & 15;
    const int quad = lane >> 4;
    const int q8   = quad * 8;
    const int mh   = w & 1;
    const int nh   = w >> 1;

    __shared__ __align__(16) unsigned short Ah[2][32][40], Al[2][32][40];
    __shared__ __align__(16) unsigned short Bh[2][32][40], Bl[2][32][40];

    const int xr  = t >> 3;          // A row 0..31 (within 32-row half)
    const int xf  = (t & 7) * 4;     // d-offset 0..28
    const int wn  = t & 31;          // B col 0..31
    const int wkb = (t >> 5) * 4;    // B k-chunk 0,4,..,28

    f32x4 acc = {0.0f, 0.0f, 0.0f, 0.0f};
    float xa[4], wv[4];

    const int cnt  = task_cnt(it4);
    const int tb   = task_base(it4);

    auto loadA = [&](int h) {
        const int base = h * 96 + tb;
        float o[4] = {0,0,0,0};
        float l = 0.0f;
        for (int s2 = 0; s2 < cnt; s2++) {
            const float* po = part_o + (size_t)(base + s2) * 2048 + (half + xr) * 32 + xf;
            float4 p0 = *(const float4*)po;
            o[0]+=p0.x; o[1]+=p0.y; o[2]+=p0.z; o[3]+=p0.w;
            l += part_l[(base + s2) * 64 + half + xr];
        }
        const float inv = 1.0f / l;
        #pragma unroll
        for (int i = 0; i < 4; i++) xa[i] = o[i] * inv;
    };
    auto loadW = [&](int k0) {
        #pragma unroll
        for (int i = 0; i < 4; i++) wv[i] = W[(k0 + wkb + i) * DM + n0 + wn];
    };
    auto storeT = [&](int b) {
        ushort4 h4, l4;
        unsigned short hh, ll;
        split_bf16(xa[0], hh, ll); h4.x = hh; l4.x = ll;
        split_bf16(xa[1], hh, ll); h4.y = hh; l4.y = ll;
        split_bf16(xa[2], hh, ll); h4.z = hh; l4.z = ll;
        split_bf16(xa[3], hh, ll); h4.w = hh; l4.w = ll;
        *(ushort4*)&Ah[b][xr][xf] = h4;
        *(ushort4*)&Al[b][xr][xf] = l4;
        split_bf16(wv[0], hh, ll); h4.x = hh; l4.x = ll;
        split_bf16(wv[1], hh, ll); h4.y = hh; l4.y = ll;
        split_bf16(wv[2], hh, ll); h4.z = hh; l4.z = ll;
        split_bf16(wv[3], hh, ll); h4.w = hh; l4.w = ll;
        *(ushort4*)&Bh[b][wn][wkb] = h4;
        *(ushort4*)&Bl[b][wn][wkb] = l4;
    };

    loadA(0); loadW(0);
    storeT(0);
    __syncthreads();

    int buf = 0;
    for (int step = 0; step < 8; step++) {
        if (step < 7) { loadA(step + 1); loadW((step + 1) * 32); }
        {
            bf16x8 ah = *(const bf16x8*)&Ah[buf][16 * mh + fm][q8];
            bf16x8 al = *(const bf16x8*)&Al[buf][16 * mh + fm][q8];
            bf16x8 bh = *(const bf16x8*)&Bh[buf][16 * nh + fm][q8];
            bf16x8 bl = *(const bf16x8*)&Bl[buf][16 * nh + fm][q8];
            acc = __builtin_amdgcn_mfma_f32_16x16x32_bf16(ah, bh, acc, 0, 0, 0);
            acc = __builtin_amdgcn_mfma_f32_16x16x32_bf16(al, bh, acc, 0, 0, 0);
            acc = __builtin_amdgcn_mfma_f32_16x16x32_bf16(ah, bl, acc, 0, 0, 0);
        }
        if (step < 7) {
            const int nb = buf ^ 1;
            storeT(nb);
            __syncthreads();
            buf = nb;
        }
    }

    {
        const int col = n0 + 16 * nh + fm;
        const float bb = bias[col];
        #pragma unroll
        for (int reg = 0; reg < 4; reg++) {
            const int row = m0 + 16 * mh + quad * 4 + reg;
            dst[row * DM + col] = acc[reg] + bb;
        }
    }
}

// ---------------------------------------------------------------------------
extern "C" void kernel_launch(void* const* d_in, const int* in_sizes, int n_in,
                              void* d_out, int out_size, void* d_ws, size_t ws_size,
                              hipStream_t stream)
{
    const float* x  = (const float*)d_in[0];
    const float* Wq = (const float*)d_in[1];
    const float* bq = (const float*)d_in[2];
    const float* Wk = (const float*)d_in[3];
    const float* bk = (const float*)d_in[4];
    const float* Wv = (const float*)d_in[5];
    const float* bv = (const float*)d_in[6];
    const float* Wo = (const float*)d_in[7];
    const float* bo = (const float*)d_in[8];
    float* out = (float*)d_out;

    float* ws      = (float*)d_ws;
    float* q       = ws;                      // [8][1024][32] = 262144
    float* k       = q + 262144;
    float* v       = k + 262144;
    float* part_o  = v + 262144;              // 8*96*2048 = 1572864
    float* part_l  = part_o + 1572864;        // 8*96*64   = 49152
    // total ~9.6 MB

    qkv_proj_kernel<<<dim3(12, 32), 256, 0, stream>>>(x, Wq, bq, Wk, bk, Wv, bv, q, k, v);
    attn_kernel<<<dim3(768), 256, 0, stream>>>(q, k, v, part_o, part_l);
    out_proj_kernel<<<dim3(8, 32), 256, 0, stream>>>(part_o, part_l, Wo, bo, out);
}

// Round 12
// 106.996 us; speedup vs baseline: 1.1045x; 1.1045x over previous
//
#include <hip/hip_runtime.h>
#include <hip/hip_bf16.h>
#include <math.h>

#define S_LEN 1024
#define DM    256
#define DU    32
#define TEMPF 5.0f
#define NS    4          // attention j-splits

typedef float    f32x4  __attribute__((ext_vector_type(4)));
typedef short    bf16x8 __attribute__((ext_vector_type(8)));   // 8 bf16 (4 VGPRs)
typedef _Float16 f16x2  __attribute__((ext_vector_type(2)));
typedef _Float16 f16x8  __attribute__((ext_vector_type(8)));

__device__ __forceinline__ unsigned short f32_to_bf16_rne(float x) {
    unsigned int b = __float_as_uint(x);
    b += 0x7FFFu + ((b >> 16) & 1u);
    return (unsigned short)(b >> 16);
}

// split f into bf16 hi + bf16 lo (hi+lo ~= f to ~2^-17 rel)
__device__ __forceinline__ void split_bf16(float f, unsigned short& h, unsigned short& l) {
    h = f32_to_bf16_rne(f);
    float hf = __uint_as_float((unsigned int)h << 16);
    l = f32_to_bf16_rne(f - hf);
}

// ---------------------------------------------------------------------------
// Kernel A: fused QKV projection via split-bf16 MFMA (R9/R10 proven).
// 64x64 tile, BK=32, 192 blocks — fat blocks amortize W staging + prologue.
// ---------------------------------------------------------------------------
__global__ __launch_bounds__(256) void qkv_proj_kernel(
    const float* __restrict__ x,
    const float* __restrict__ Wq, const float* __restrict__ bq,
    const float* __restrict__ Wk, const float* __restrict__ bk,
    const float* __restrict__ Wv, const float* __restrict__ bv,
    float* __restrict__ qo, float* __restrict__ ko, float* __restrict__ vo)
{
    const int n0g = blockIdx.x * 64;       // 0..704 over [Wq|Wk|Wv] cols
    const int mat = n0g >> 8;
    const int n0  = n0g & 255;
    const float* __restrict__ W    = (mat == 0) ? Wq : ((mat == 1) ? Wk : Wv);
    const float* __restrict__ bias = (mat == 0) ? bq : ((mat == 1) ? bk : bv);
    float* __restrict__ dst        = (mat == 0) ? qo : ((mat == 1) ? ko : vo);

    const int m0   = blockIdx.y * 64;
    const int t    = threadIdx.x;
    const int w    = t >> 6;
    const int lane = t & 63;
    const int fm   = lane & 15;
    const int quad = lane >> 4;
    const int q8   = quad * 8;

    __shared__ __align__(16) unsigned short Ah[2][64][40], Al[2][64][40];
    __shared__ __align__(16) unsigned short Bh[2][64][40], Bl[2][64][40];

    const int xr  = t >> 2;
    const int xf  = (t & 3) * 8;
    const int wn  = t & 63;
    const int wkc = (t >> 6) * 8;

    f32x4 acc[4];
    #pragma unroll
    for (int nt = 0; nt < 4; nt++)
        #pragma unroll
        for (int i = 0; i < 4; i++) acc[nt][i] = 0.0f;

    const float* xbase = x + (m0 + xr) * DM + xf;
    float xa[8], wv[8];

    {
        float4 a0 = *(const float4*)xbase;
        float4 a1 = *(const float4*)(xbase + 4);
        xa[0]=a0.x; xa[1]=a0.y; xa[2]=a0.z; xa[3]=a0.w;
        xa[4]=a1.x; xa[5]=a1.y; xa[6]=a1.z; xa[7]=a1.w;
        #pragma unroll
        for (int i = 0; i < 8; i++) wv[i] = W[(wkc + i) * DM + n0 + wn];
    }
    {
        bf16x8 vh, vl;
        #pragma unroll
        for (int i = 0; i < 8; i++) { unsigned short h,l; split_bf16(xa[i],h,l); vh[i]=(short)h; vl[i]=(short)l; }
        *(bf16x8*)&Ah[0][xr][xf] = vh; *(bf16x8*)&Al[0][xr][xf] = vl;
        #pragma unroll
        for (int i = 0; i < 8; i++) { unsigned short h,l; split_bf16(wv[i],h,l); vh[i]=(short)h; vl[i]=(short)l; }
        *(bf16x8*)&Bh[0][wn][wkc] = vh; *(bf16x8*)&Bl[0][wn][wkc] = vl;
    }
    __syncthreads();

    int buf = 0;
    for (int step = 0; step < 8; step++) {
        if (step < 7) {
            const float* xp = xbase + (step + 1) * 32;
            float4 a0 = *(const float4*)xp;
            float4 a1 = *(const float4*)(xp + 4);
            xa[0]=a0.x; xa[1]=a0.y; xa[2]=a0.z; xa[3]=a0.w;
            xa[4]=a1.x; xa[5]=a1.y; xa[6]=a1.z; xa[7]=a1.w;
            #pragma unroll
            for (int i = 0; i < 8; i++)
                wv[i] = W[((step + 1) * 32 + wkc + i) * DM + n0 + wn];
        }
        {
            bf16x8 ah = *(const bf16x8*)&Ah[buf][16 * w + fm][q8];
            bf16x8 al = *(const bf16x8*)&Al[buf][16 * w + fm][q8];
            #pragma unroll
            for (int nt = 0; nt < 4; nt++) {
                bf16x8 bh = *(const bf16x8*)&Bh[buf][nt * 16 + fm][q8];
                bf16x8 bl = *(const bf16x8*)&Bl[buf][nt * 16 + fm][q8];
                acc[nt] = __builtin_amdgcn_mfma_f32_16x16x32_bf16(ah, bh, acc[nt], 0, 0, 0);
                acc[nt] = __builtin_amdgcn_mfma_f32_16x16x32_bf16(al, bh, acc[nt], 0, 0, 0);
                acc[nt] = __builtin_amdgcn_mfma_f32_16x16x32_bf16(ah, bl, acc[nt], 0, 0, 0);
            }
        }
        if (step < 7) {
            const int nb = buf ^ 1;
            bf16x8 vh, vl;
            #pragma unroll
            for (int i = 0; i < 8; i++) { unsigned short h,l; split_bf16(xa[i],h,l); vh[i]=(short)h; vl[i]=(short)l; }
            *(bf16x8*)&Ah[nb][xr][xf] = vh; *(bf16x8*)&Al[nb][xr][xf] = vl;
            #pragma unroll
            for (int i = 0; i < 8; i++) { unsigned short h,l; split_bf16(wv[i],h,l); vh[i]=(short)h; vl[i]=(short)l; }
            *(bf16x8*)&Bh[nb][wn][wkc] = vh; *(bf16x8*)&Bl[nb][wn][wkc] = vl;
            __syncthreads();
            buf = nb;
        }
    }

    #pragma unroll
    for (int nt = 0; nt < 4; nt++) {
        const int col = n0 + nt * 16 + fm;
        const float bb = bias[col];
        const int hh = col >> 5;
        const int dd = col & 31;
        float* dp = dst + hh * (S_LEN * DU) + dd;
        #pragma unroll
        for (int reg = 0; reg < 4; reg++) {
            const int row = m0 + 16 * w + quad * 4 + reg;
            float val = acc[nt][reg] + bb;
            if (mat < 2) val = 1.0f / (1.0f + __expf(-val));
            dp[row * DU] = val;
        }
    }
}

// ---------------------------------------------------------------------------
// Kernel B: fuzzy-implication attention (R10 proven).  512 blocks =
// 8h x 16 it4 x NS=4, LPT; f16-packed score, bf16 MFMA PV, no online max.
// ---------------------------------------------------------------------------
__global__ __launch_bounds__(256, 2) void attn_kernel(
    const float* __restrict__ q, const float* __restrict__ k,
    const float* __restrict__ v,
    float* __restrict__ part_o, float* __restrict__ part_l)
{
    const int bid = blockIdx.x;
    const int it4 = 15 - (bid >> 5);      // LPT: heavy first
    const int sub = bid & 31;
    const int h   = sub & 7;
    const int s   = sub >> 3;             // split 0..NS-1
    const int t   = threadIdx.x;
    const int r   = t >> 4;               // 0..15
    const int c   = t & 15;               // 0..15
    const int w   = t >> 6;               // wave 0..3
    const int i0  = it4 * 64;

    __shared__ __align__(16) _Float16       Kh[64][40];   // [j][d] f16 (score)
    __shared__ __align__(16) unsigned short Vt[32][88];   // [d][j] bf16 (B-op)
    __shared__ __align__(16) unsigned short Ps[64][88];   // [row][j] bf16 (A-op)

    // Q rows as f16x2 pairs
    f16x2 qh[4][16];
    #pragma unroll
    for (int kq = 0; kq < 4; kq++) {
        const float* qrow = q + h * (S_LEN * DU) + (i0 + r + 16 * kq) * DU;
        #pragma unroll
        for (int d4 = 0; d4 < 8; d4++) {
            float4 qv = *(const float4*)&qrow[d4 * 4];
            qh[kq][d4*2+0] = (f16x2){(_Float16)qv.x, (_Float16)qv.y};
            qh[kq][d4*2+1] = (f16x2){(_Float16)qv.z, (_Float16)qv.w};
        }
    }
    const f16x2 one2  = {(_Float16)1.0f, (_Float16)1.0f};
    const f16x2 zero2 = {(_Float16)0.0f, (_Float16)0.0f};

    float lpart[4] = {0.0f, 0.0f, 0.0f, 0.0f};
    f32x4 acc0 = {0.0f, 0.0f, 0.0f, 0.0f};
    f32x4 acc1 = {0.0f, 0.0f, 0.0f, 0.0f};

    const int jr = t >> 2;
    const int d0 = (t & 3) * 8;
    const float* kbase = k + h * (S_LEN * DU);
    const float* vbase = v + h * (S_LEN * DU);

    const int lane = t & 63;
    const int m    = lane & 15;
    const int quad = lane >> 4;

    const int njt = it4 + 1;
    float4 ka, kb, va, vb;
    if (s < njt) {
        const float* kp = kbase + (s * 64 + jr) * DU + d0;
        const float* vp = vbase + (s * 64 + jr) * DU + d0;
        ka = *(const float4*)kp; kb = *(const float4*)(kp + 4);
        va = *(const float4*)vp; vb = *(const float4*)(vp + 4);
    }

    for (int jt = s; jt < njt; jt += NS) {
        __syncthreads();
        {
            float kv[8] = {ka.x, ka.y, ka.z, ka.w, kb.x, kb.y, kb.z, kb.w};
            f16x8 kh8;
            #pragma unroll
            for (int i = 0; i < 8; i++) kh8[i] = (_Float16)kv[i];
            *(f16x8*)&Kh[jr][d0] = kh8;
            float vv[8] = {va.x, va.y, va.z, va.w, vb.x, vb.y, vb.z, vb.w};
            #pragma unroll
            for (int i = 0; i < 8; i++)
                Vt[d0 + i][jr] = f32_to_bf16_rne(vv[i]);
        }
        __syncthreads();
        if (jt + NS < njt) {
            const float* kp = kbase + ((jt + NS) * 64 + jr) * DU + d0;
            const float* vp = vbase + ((jt + NS) * 64 + jr) * DU + d0;
            ka = *(const float4*)kp; kb = *(const float4*)(kp + 4);
            va = *(const float4*)vp; vb = *(const float4*)(vp + 4);
        }

        // ---- phase 1: f16-packed scores -> p -> Ps bf16 + l partials ----
        #pragma unroll
        for (int q4 = 0; q4 < 4; q4++) {
            const int jj  = c + q4 * 16;
            const int jgl = jt * 64 + jj;
            float sacc[4] = {0.0f, 0.0f, 0.0f, 0.0f};
            #pragma unroll
            for (int d8 = 0; d8 < 4; d8++) {
                f16x8 k8 = *(const f16x8*)&Kh[jj][d8 * 8];
                #pragma unroll
                for (int p2 = 0; p2 < 4; p2++) {
                    f16x2 kk = {k8[2*p2], k8[2*p2+1]};
                    #pragma unroll
                    for (int kq = 0; kq < 4; kq++) {
                        f16x2 diff = qh[kq][d8*4+p2] - kk;
                        f16x2 mx = __builtin_elementwise_max(diff, zero2);
#if defined(__has_builtin) && __has_builtin(__builtin_amdgcn_fdot2)
                        sacc[kq] = __builtin_amdgcn_fdot2(mx, one2, sacc[kq], false);
#else
                        sacc[kq] += (float)mx[0] + (float)mx[1];
#endif
                    }
                }
            }
            #pragma unroll
            for (int kq = 0; kq < 4; kq++) {
                const int ig = i0 + r + 16 * kq;
                const float p = (jgl <= ig)
                    ? __expf(TEMPF - (TEMPF / 32.0f) * sacc[kq]) : 0.0f;
                lpart[kq] += p;
                Ps[r + 16 * kq][jj] = f32_to_bf16_rne(p);
            }
        }
        __syncthreads();

        // ---- phase 2: PV via MFMA ----
        #pragma unroll
        for (int kc = 0; kc < 2; kc++) {
            bf16x8 a  = *(const bf16x8*)&Ps[16 * w + m][kc * 32 + quad * 8];
            bf16x8 b0 = *(const bf16x8*)&Vt[m]     [kc * 32 + quad * 8];
            bf16x8 b1 = *(const bf16x8*)&Vt[m + 16][kc * 32 + quad * 8];
            acc0 = __builtin_amdgcn_mfma_f32_16x16x32_bf16(a, b0, acc0, 0, 0, 0);
            acc1 = __builtin_amdgcn_mfma_f32_16x16x32_bf16(a, b1, acc1, 0, 0, 0);
        }
    }

    #pragma unroll
    for (int off = 8; off; off >>= 1)
        #pragma unroll
        for (int kq = 0; kq < 4; kq++)
            lpart[kq] += __shfl_xor(lpart[kq], off, 16);

    const int pbase = (h * 16 + it4) * NS + s;
    float* po = part_o + (size_t)pbase * 2048;
    #pragma unroll
    for (int reg = 0; reg < 4; reg++) {
        const int row = 16 * w + quad * 4 + reg;
        po[row * 32 + m]      = acc0[reg];
        po[row * 32 + m + 16] = acc1[reg];
    }
    if (c == 0) {
        #pragma unroll
        for (int kq = 0; kq < 4; kq++)
            part_l[pbase * 64 + r + 16 * kq] = lpart[kq];
    }
}

// ---------------------------------------------------------------------------
// Kernel C: output projection + fused combine (R10 proven).  128 blocks,
// 32-wide n-tiles, 64-row m-tiles.  Split-bf16 3-MFMA core.
// ---------------------------------------------------------------------------
__global__ __launch_bounds__(256) void out_proj_kernel(
    const float* __restrict__ part_o, const float* __restrict__ part_l,
    const float* __restrict__ W, const float* __restrict__ bias,
    float* __restrict__ dst)
{
    const int n0  = blockIdx.x * 32;
    const int it4 = blockIdx.y;
    const int m0  = it4 * 64;
    const int t    = threadIdx.x;
    const int w    = t >> 6;
    const int lane = t & 63;
    const int fm   = lane & 15;
    const int quad = lane >> 4;
    const int q8   = quad * 8;

    __shared__ __align__(16) unsigned short Ah[2][64][40], Al[2][64][40];
    __shared__ __align__(16) unsigned short Bh[2][32][40], Bl[2][32][40];

    const int xr  = t >> 2;          // A row 0..63
    const int xf  = (t & 3) * 8;     // d-offset
    const int wn  = t & 31;          // B col 0..31
    const int wkb = (t >> 5) * 4;    // B k-chunk 0,4,..,28

    f32x4 acc[2];
    #pragma unroll
    for (int nt = 0; nt < 2; nt++)
        #pragma unroll
        for (int i = 0; i < 4; i++) acc[nt][i] = 0.0f;

    float xa[8], wv[4];

    auto loadA = [&](int h) {
        const int base = (h * 16 + it4) * NS;
        float o[8] = {0,0,0,0,0,0,0,0};
        float l = 0.0f;
        #pragma unroll
        for (int s2 = 0; s2 < NS; s2++) {
            const float* po = part_o + (size_t)(base + s2) * 2048 + xr * 32 + xf;
            float4 p0 = *(const float4*)po;
            float4 p1 = *(const float4*)(po + 4);
            o[0]+=p0.x; o[1]+=p0.y; o[2]+=p0.z; o[3]+=p0.w;
            o[4]+=p1.x; o[5]+=p1.y; o[6]+=p1.z; o[7]+=p1.w;
            l += part_l[(base + s2) * 64 + xr];
        }
        const float inv = 1.0f / l;
        #pragma unroll
        for (int i = 0; i < 8; i++) xa[i] = o[i] * inv;
    };
    auto loadW = [&](int k0) {
        #pragma unroll
        for (int i = 0; i < 4; i++) wv[i] = W[(k0 + wkb + i) * DM + n0 + wn];
    };
    auto storeT = [&](int b) {
        bf16x8 vh, vl;
        #pragma unroll
        for (int i = 0; i < 8; i++) { unsigned short h,l; split_bf16(xa[i],h,l); vh[i]=(short)h; vl[i]=(short)l; }
        *(bf16x8*)&Ah[b][xr][xf] = vh; *(bf16x8*)&Al[b][xr][xf] = vl;
        ushort4 bh4, bl4;
        unsigned short hh, ll;
        split_bf16(wv[0], hh, ll); bh4.x = hh; bl4.x = ll;
        split_bf16(wv[1], hh, ll); bh4.y = hh; bl4.y = ll;
        split_bf16(wv[2], hh, ll); bh4.z = hh; bl4.z = ll;
        split_bf16(wv[3], hh, ll); bh4.w = hh; bl4.w = ll;
        *(ushort4*)&Bh[b][wn][wkb] = bh4;
        *(ushort4*)&Bl[b][wn][wkb] = bl4;
    };

    loadA(0); loadW(0);
    storeT(0);
    __syncthreads();

    int buf = 0;
    for (int step = 0; step < 8; step++) {
        if (step < 7) { loadA(step + 1); loadW((step + 1) * 32); }
        {
            bf16x8 ah = *(const bf16x8*)&Ah[buf][16 * w + fm][q8];
            bf16x8 al = *(const bf16x8*)&Al[buf][16 * w + fm][q8];
            #pragma unroll
            for (int nt = 0; nt < 2; nt++) {
                bf16x8 bh = *(const bf16x8*)&Bh[buf][nt * 16 + fm][q8];
                bf16x8 bl = *(const bf16x8*)&Bl[buf][nt * 16 + fm][q8];
                acc[nt] = __builtin_amdgcn_mfma_f32_16x16x32_bf16(ah, bh, acc[nt], 0, 0, 0);
                acc[nt] = __builtin_amdgcn_mfma_f32_16x16x32_bf16(al, bh, acc[nt], 0, 0, 0);
                acc[nt] = __builtin_amdgcn_mfma_f32_16x16x32_bf16(ah, bl, acc[nt], 0, 0, 0);
            }
        }
        if (step < 7) {
            const int nb = buf ^ 1;
            storeT(nb);
            __syncthreads();
            buf = nb;
        }
    }

    #pragma unroll
    for (int nt = 0; nt < 2; nt++) {
        const int col = n0 + nt * 16 + fm;
        const float bb = bias[col];
        #pragma unroll
        for (int reg = 0; reg < 4; reg++) {
            const int row = m0 + 16 * w + quad * 4 + reg;
            dst[row * DM + col] = acc[nt][reg] + bb;
        }
    }
}

// ---------------------------------------------------------------------------
extern "C" void kernel_launch(void* const* d_in, const int* in_sizes, int n_in,
                              void* d_out, int out_size, void* d_ws, size_t ws_size,
                              hipStream_t stream)
{
    const float* x  = (const float*)d_in[0];
    const float* Wq = (const float*)d_in[1];
    const float* bq = (const float*)d_in[2];
    const float* Wk = (const float*)d_in[3];
    const float* bk = (const float*)d_in[4];
    const float* Wv = (const float*)d_in[5];
    const float* bv = (const float*)d_in[6];
    const float* Wo = (const float*)d_in[7];
    const float* bo = (const float*)d_in[8];
    float* out = (float*)d_out;

    float* ws      = (float*)d_ws;
    float* q       = ws;                      // [8][1024][32] = 262144
    float* k       = q + 262144;
    float* v       = k + 262144;
    float* part_o  = v + 262144;              // 8*16*NS*2048 = 1048576
    float* part_l  = part_o + 1048576;        // 8*16*NS*64   = 32768
    // total ~7.5 MB

    qkv_proj_kernel<<<dim3(12, 16), 256, 0, stream>>>(x, Wq, bq, Wk, bk, Wv, bv, q, k, v);
    attn_kernel<<<dim3(512), 256, 0, stream>>>(q, k, v, part_o, part_l);
    out_proj_kernel<<<dim3(8, 16), 256, 0, stream>>>(part_o, part_l, Wo, bo, out);
}